// Round 15
// baseline (1823.636 us; speedup 1.0000x reference)
//
#include <hip/hip_runtime.h>

#define BN_   16
#define NPTS  4096
#define DFEAT 6
#define SCTR  1024
#define KNN   32
#define RTOT  (BN_*SCTR*KNN)   /* 524288 rows */
#define EPSV  1e-5f
#define RNF   524288.0f
#define NREP  64               /* replicated stats copies */

__device__ __forceinline__ float fmulx(float a, float b){ return __fmul_rn(a,b); }
__device__ __forceinline__ float faddx(float a, float b){ return __fadd_rn(a,b); }
__device__ __forceinline__ float fsubx(float a, float b){ return __fsub_rn(a,b); }
// naive (non-FMA) sum of squares — LOCKED by R5/R6 pass.
__device__ __forceinline__ float sq3x(float x, float y, float z){
  return faddx(faddx(fmulx(x,x), fmulx(y,y)), fmulx(z,z));
}
// FMA-contracted inner product (matches np einsum) — LOCKED by R5 pass.
__device__ __forceinline__ float dot3fma(float ax, float ay, float az,
                                         float bx, float by, float bz){
  return __fmaf_rn(az, bz, __fmaf_rn(ay, by, __fmul_rn(ax, bx)));
}

__device__ __forceinline__ unsigned fkey(float f){
  unsigned u = __float_as_uint(f);
  return (u & 0x80000000u) ? ~u : (u | 0x80000000u);
}
__device__ __forceinline__ float funkey(unsigned k){
  return (k & 0x80000000u) ? __uint_as_float(k & 0x7fffffffu) : __uint_as_float(~k);
}

// ---------------- DPP wave64 reductions (VALU-only; proven on HW in R12).
template<int CTRL>
__device__ __forceinline__ unsigned dpp_mv(unsigned v){
  return (unsigned)__builtin_amdgcn_update_dpp((int)v, (int)v, CTRL, 0xf, 0xf, false);
}
__device__ __forceinline__ unsigned wave_umax_b(unsigned v){
  unsigned o;
  o=dpp_mv<0x111>(v); v=v>o?v:o;   // row_shr:1
  o=dpp_mv<0x112>(v); v=v>o?v:o;   // row_shr:2
  o=dpp_mv<0x114>(v); v=v>o?v:o;   // row_shr:4
  o=dpp_mv<0x118>(v); v=v>o?v:o;   // row_shr:8
  o=dpp_mv<0x142>(v); v=v>o?v:o;   // row_bcast:15
  o=dpp_mv<0x143>(v); v=v>o?v:o;   // row_bcast:31
  return (unsigned)__builtin_amdgcn_readlane((int)v, 63);
}
__device__ __forceinline__ unsigned wave_umin_b(unsigned v){
  unsigned o;
  o=dpp_mv<0x111>(v); v=v<o?v:o;
  o=dpp_mv<0x112>(v); v=v<o?v:o;
  o=dpp_mv<0x114>(v); v=v<o?v:o;
  o=dpp_mv<0x118>(v); v=v<o?v:o;
  o=dpp_mv<0x142>(v); v=v<o?v:o;
  o=dpp_mv<0x143>(v); v=v<o?v:o;
  return (unsigned)__builtin_amdgcn_readlane((int)v, 63);
}

// ---------------------------------------------------------------- FPS
// R12 structure but the per-iteration __syncthreads is replaced by a tagged
// spin-poll on the slots. Slot u64 = M<<32 | (it<<12) | (4095-minj):
// winner u64-max semantics identical (same it tag across slots -> compare falls
// to 4095-j -> min j). Parity double-buffer bounds wave drift to 1 iteration,
// so a slot is never overwritten before every wave consumed it (write for it+2
// requires polling it+1, which requires all waves wrote it+1, which happens
// only after they consumed it). Selection math bit-identical to R12.
__global__ __launch_bounds__(256) void k_fps(const float* __restrict__ xyz,
                                             float* __restrict__ cxyz){
  const int b = blockIdx.x, tid = threadIdx.x;
  const int wave = tid>>6, lane = tid&63;
  const float* X = xyz + (size_t)b*NPTS*3;
  __shared__ float Xl[NPTS*3];
  __shared__ float Cl[SCTR*3];
  __shared__ unsigned long long slot[2][4];
  for(int i=tid;i<NPTS*3;i+=256) Xl[i]=X[i];
  if(tid<8) slot[tid>>2][tid&3] = 0ull;      // tag=0, never polled (it starts at 1)
  __syncthreads();
  float px[16],py[16],pz[16],mind[16];
  const float c0x=Xl[0], c0y=Xl[1], c0z=Xl[2];
#pragma unroll
  for(int t=0;t<16;t++){
    const int j = lane + 64*(wave*16+t);
    px[t]=Xl[j*3]; py[t]=Xl[j*3+1]; pz[t]=Xl[j*3+2];
    mind[t]=sq3x(fsubx(px[t],c0x), fsubx(py[t],c0y), fsubx(pz[t],c0z));
  }
  if(tid==0){ Cl[0]=c0x; Cl[1]=c0y; Cl[2]=c0z; }
  float bv=-1.0f; int bj=0x7fffffff;
#pragma unroll
  for(int t=0;t<16;t++){
    const int j = lane + 64*(wave*16+t);
    if(mind[t]>bv){ bv=mind[t]; bj=j; }
  }
  for(int it=1; it<SCTR; ++it){
    const unsigned uv = __float_as_uint(bv);
    const unsigned M  = wave_umax_b(uv);
    const unsigned nj = (uv == M) ? (4095u - (unsigned)bj) : 0u;  // bj in [0,4095]
    const unsigned NJ = wave_umax_b(nj);                          // = 4095 - minj
    const unsigned long long kwave =
        ((unsigned long long)M<<32) | (unsigned)((it<<12) | (int)NJ);
    volatile unsigned long long* S = &slot[it&1][0];
    if(lane==0) S[wave] = kwave;
    const unsigned tg = (unsigned)it & 0x3FFu;
    unsigned long long s0,s1,s2,s3;
    for(;;){
      s0=S[0]; s1=S[1]; s2=S[2]; s3=S[3];
      if( (((unsigned)(s0>>12))&0x3FFu)==tg && (((unsigned)(s1>>12))&0x3FFu)==tg &&
          (((unsigned)(s2>>12))&0x3FFu)==tg && (((unsigned)(s3>>12))&0x3FFu)==tg ) break;
    }
    unsigned long long ka = s0>s1?s0:s1;
    unsigned long long kb = s2>s3?s2:s3;
    unsigned long long kw = ka>kb?ka:kb;
    const int w = 4095 - (int)(kw & 0xFFFull);
    const float cx=Xl[w*3], cy=Xl[w*3+1], cz=Xl[w*3+2];
    if(tid==0){ Cl[it*3]=cx; Cl[it*3+1]=cy; Cl[it*3+2]=cz; }
    bv=-1.0f; bj=0x7fffffff;
#pragma unroll
    for(int t=0;t<16;t++){
      float d = sq3x(fsubx(px[t],cx), fsubx(py[t],cy), fsubx(pz[t],cz));
      float nm = fminf(mind[t], d);
      mind[t]=nm;
      const int j = lane + 64*(wave*16+t);
      if(nm>bv){ bv=nm; bj=j; }
    }
  }
  __syncthreads();
  float* O = cxyz + (size_t)b*SCTR*3;
  for(int i=tid;i<SCTR*3;i+=256) O[i]=Cl[i];
}

// ------------------------------------------- 32-NN select (R12 version, proven)
__global__ __launch_bounds__(256) void k_select(const float* __restrict__ xyz,
                                                const float* __restrict__ cxyz,
                                                int* __restrict__ gidx){
  const int lane = threadIdx.x & 63;
  const int cid  = blockIdx.x*4 + (threadIdx.x>>6);
  const int b = cid>>10;
  const float* X = xyz + (size_t)b*NPTS*3;
  const float* C = cxyz + (size_t)cid*3;
  const float cx=C[0], cy=C[1], cz=C[2];
  const float a2 = sq3x(cx,cy,cz);
  float d[64];
#pragma unroll
  for(int t=0;t<64;t++){
    int j = lane + (t<<6);
    float x=X[j*3], y=X[j*3+1], z=X[j*3+2];
    float b2 = sq3x(x,y,z);
    float dt = dot3fma(cx,cy,cz, x,y,z);
    float dd = fsubx(faddx(a2,b2), fmulx(2.0f,dt));
    d[t] = fmaxf(dd, 0.0f);
  }
  unsigned long long taken = 0ull;
  int* out = gidx + (size_t)cid*KNN;
#pragma unroll 1
  for(int r=0;r<KNN;r++){
    float mv = 3.0e38f; int mt = 63;
#pragma unroll
    for(int t=0;t<64;t++){
      if(!(taken & (1ull<<t)) && d[t] < mv){ mv = d[t]; mt = t; }
    }
    const unsigned um = __float_as_uint(mv);
    const unsigned Mw = wave_umin_b(um);
    const unsigned jc = (um == Mw) ? (unsigned)(lane + (mt<<6)) : 0xffffffffu;
    const unsigned WJ = wave_umin_b(jc);
    if(lane == (int)(WJ & 63u)){
      out[r] = (int)WJ;
      taken |= (1ull << (WJ >> 6));
    }
  }
}

// ------------------------------------------------- shared tile helpers
__device__ __forceinline__ void stage_in(float* INt, int rbase,
                                         const float* __restrict__ xyz,
                                         const float* __restrict__ feat,
                                         const float* __restrict__ cxyz,
                                         const int* __restrict__ gidx){
  const int tid = threadIdx.x;
  const int row = tid>>2, sub = tid&3;
  const int r  = rbase + row;
  const int bb = r>>15, ss=(r>>5)&1023;
  const int idx = gidx[r];
  if(sub==0){
    const float* P = xyz  + ((size_t)bb*NPTS + idx)*3;
    const float* C = cxyz + ((size_t)(bb*SCTR)+ss)*3;
    INt[0*68+row] = P[0]-C[0];
    INt[1*68+row] = P[1]-C[1];
    INt[2*68+row] = P[2]-C[2];
  }else{
    const float* F = feat + ((size_t)bb*NPTS + idx)*6;
    const int c = (sub-1)*2;
    INt[(3+c)*68+row] = F[c];
    INt[(4+c)*68+row] = F[c+1];
  }
}

__device__ __forceinline__ void gemm1(const float* INt, const float* __restrict__ W1,
                                      int rt, int ct, float acc[4][4]){
#pragma unroll
  for(int i=0;i<4;i++)
#pragma unroll
    for(int j=0;j<4;j++) acc[i][j]=0.f;
#pragma unroll
  for(int c=0;c<9;c++){
    const float4 a = *(const float4*)&INt[c*68 + rt*4];
    const float4 w = *(const float4*)&W1[c*64 + ct*4];
    const float av[4]={a.x,a.y,a.z,a.w}, wv[4]={w.x,w.y,w.z,w.w};
#pragma unroll
    for(int i=0;i<4;i++)
#pragma unroll
      for(int j=0;j<4;j++) acc[i][j] += av[i]*wv[j];
  }
}

// fold one channel across the NREP replicated copies (seg = base offset)
__device__ __forceinline__ float fold_rep(const float* __restrict__ pstats, int off){
  float s=0.f;
#pragma unroll 8
  for(int c=0;c<NREP;c++) s += pstats[c*512 + off];
  return s;
}

// ---------------------------------------------------------------- layer-1 stats
// atomics into replicated pstats[blockIdx&63][0..127]
__global__ __launch_bounds__(256) void k_stats1(const float* __restrict__ xyz,
                                                const float* __restrict__ feat,
                                                const float* __restrict__ cxyz,
                                                const int* __restrict__ gidx,
                                                const float* __restrict__ W1,
                                                float* __restrict__ pstats){
  __shared__ __align__(16) float INt[9*68];
  __shared__ float sb[64], qb[64];
  const int tid=threadIdx.x;
  if(tid<64){ sb[tid]=0.f; qb[tid]=0.f; }
  stage_in(INt, blockIdx.x*64, xyz, feat, cxyz, gidx);
  __syncthreads();
  const int rt=tid&15, ct=tid>>4;
  float acc[4][4];
  gemm1(INt, W1, rt, ct, acc);
#pragma unroll
  for(int j=0;j<4;j++){
    float s=0.f, q=0.f;
#pragma unroll
    for(int i=0;i<4;i++){ float v=acc[i][j]; s+=v; q+=v*v; }
    atomicAdd(&sb[ct*4+j], s); atomicAdd(&qb[ct*4+j], q);
  }
  __syncthreads();
  if(tid<64){
    float* ps = pstats + (size_t)(blockIdx.x & (NREP-1))*512;
    atomicAdd(&ps[tid], sb[tid]); atomicAdd(&ps[64+tid], qb[tid]);
  }
}

// -------------------------------------- layer-2 stats core (optionally writes Z2)
template<bool WRITEZ>
__device__ __forceinline__ void stats2_body(const float* xyz, const float* feat,
                                            const float* cxyz, const int* gidx,
                                            const float* W1, const float* g1,
                                            const float* b1, const float* __restrict__ W2,
                                            float* pstats, float* Z2){
  __shared__ __align__(16) float INt[9*68];
  __shared__ __align__(16) float A1t[64*68];
  __shared__ float af1A[64], af1B[64];
  __shared__ float sb[64], qb[64];
  const int tid=threadIdx.x;
  if(tid<64){
    float sm = fold_rep(pstats, tid);
    float sq = fold_rep(pstats, 64+tid);
    float m  = sm/RNF;
    float vv = sq/RNF - m*m;
    float A  = rsqrtf(vv+EPSV)*g1[tid];
    af1A[tid]=A; af1B[tid]=b1[tid]-m*A;
    sb[tid]=0.f; qb[tid]=0.f;
  }
  stage_in(INt, blockIdx.x*64, xyz, feat, cxyz, gidx);
  __syncthreads();
  const int rt=tid&15, ct=tid>>4;
  float acc1[4][4];
  gemm1(INt, W1, rt, ct, acc1);
#pragma unroll
  for(int j=0;j<4;j++){
    const int o=ct*4+j; const float A=af1A[o], Bc=af1B[o];
#pragma unroll
    for(int i=0;i<4;i++) A1t[o*68 + rt*4+i] = fmaxf(acc1[i][j]*A+Bc, 0.f);
  }
  __syncthreads();
  float acc2[4][4];
#pragma unroll
  for(int i=0;i<4;i++)
#pragma unroll
    for(int j=0;j<4;j++) acc2[i][j]=0.f;
#pragma unroll
  for(int c=0;c<64;c++){
    const float4 a = *(const float4*)&A1t[c*68 + rt*4];
    const float4 w = *(const float4*)&W2[c*64 + ct*4];
    const float av[4]={a.x,a.y,a.z,a.w}, wv[4]={w.x,w.y,w.z,w.w};
#pragma unroll
    for(int i=0;i<4;i++)
#pragma unroll
      for(int j=0;j<4;j++) acc2[i][j] += av[i]*wv[j];
  }
  if(WRITEZ){
#pragma unroll
    for(int i=0;i<4;i++){
      float4 v = make_float4(acc2[i][0],acc2[i][1],acc2[i][2],acc2[i][3]);
      *(float4*)&Z2[((size_t)blockIdx.x*64 + rt*4+i)*64 + ct*4] = v;
    }
  }
#pragma unroll
  for(int j=0;j<4;j++){
    float s=0.f, q=0.f;
#pragma unroll
    for(int i=0;i<4;i++){ float v=acc2[i][j]; s+=v; q+=v*v; }
    atomicAdd(&sb[ct*4+j], s); atomicAdd(&qb[ct*4+j], q);
  }
  __syncthreads();
  if(tid<64){
    float* ps = pstats + (size_t)(blockIdx.x & (NREP-1))*512;
    atomicAdd(&ps[128+tid], sb[tid]); atomicAdd(&ps[192+tid], qb[tid]);
  }
}

__global__ __launch_bounds__(256) void k_stats2(const float* __restrict__ xyz,
                                                const float* __restrict__ feat,
                                                const float* __restrict__ cxyz,
                                                const int* __restrict__ gidx,
                                                const float* __restrict__ W1,
                                                const float* __restrict__ g1,
                                                const float* __restrict__ b1,
                                                const float* __restrict__ W2,
                                                float* __restrict__ pstats){
  stats2_body<false>(xyz,feat,cxyz,gidx,W1,g1,b1,W2,pstats,nullptr);
}
__global__ __launch_bounds__(256) void k_stats2m(const float* __restrict__ xyz,
                                                 const float* __restrict__ feat,
                                                 const float* __restrict__ cxyz,
                                                 const int* __restrict__ gidx,
                                                 const float* __restrict__ W1,
                                                 const float* __restrict__ g1,
                                                 const float* __restrict__ b1,
                                                 const float* __restrict__ W2,
                                                 float* __restrict__ pstats,
                                                 float* __restrict__ Z2){
  stats2_body<true>(xyz,feat,cxyz,gidx,W1,g1,b1,W2,pstats,Z2);
}

// ------------------------------------------- layer-3 (fallback: full recompute)
__global__ __launch_bounds__(256) void k_layer3(const float* __restrict__ xyz,
                                                const float* __restrict__ feat,
                                                const float* __restrict__ cxyz,
                                                const int* __restrict__ gidx,
                                                const float* __restrict__ W1,
                                                const float* __restrict__ g1,
                                                const float* __restrict__ b1,
                                                const float* __restrict__ W2,
                                                const float* __restrict__ g2,
                                                const float* __restrict__ b2,
                                                const float* __restrict__ W3,
                                                float* __restrict__ pstats,
                                                float* __restrict__ premax){
  __shared__ __align__(16) float INt[9*68];
  __shared__ __align__(16) float A1t[64*68];
  __shared__ float af1A[64], af1B[64], af2A[64], af2B[64];
  __shared__ unsigned mx[256];
  __shared__ float s3b[256], q3b[256];
  const int tid=threadIdx.x;
  if(tid<64){
    float sm = fold_rep(pstats, tid);
    float sq = fold_rep(pstats, 64+tid);
    float m  = sm/RNF;
    float vv = sq/RNF - m*m;
    float A  = rsqrtf(vv+EPSV)*g1[tid];
    af1A[tid]=A; af1B[tid]=b1[tid]-m*A;
    float sm2 = fold_rep(pstats, 128+tid);
    float sq2 = fold_rep(pstats, 192+tid);
    float m2 = sm2/RNF;
    float v2 = sq2/RNF - m2*m2;
    float A2 = rsqrtf(v2+EPSV)*g2[tid];
    af2A[tid]=A2; af2B[tid]=b2[tid]-m2*A2;
  }
  mx[tid]=0u; s3b[tid]=0.f; q3b[tid]=0.f;
  stage_in(INt, blockIdx.x*64, xyz, feat, cxyz, gidx);
  __syncthreads();
  const int rt=tid&15, ct=tid>>4;
  float acc1[4][4];
  gemm1(INt, W1, rt, ct, acc1);
#pragma unroll
  for(int j=0;j<4;j++){
    const int o=ct*4+j; const float A=af1A[o], Bc=af1B[o];
#pragma unroll
    for(int i=0;i<4;i++) A1t[o*68 + rt*4+i] = fmaxf(acc1[i][j]*A+Bc, 0.f);
  }
  __syncthreads();
  float acc2[4][4];
#pragma unroll
  for(int i=0;i<4;i++)
#pragma unroll
    for(int j=0;j<4;j++) acc2[i][j]=0.f;
#pragma unroll
  for(int c=0;c<64;c++){
    const float4 a = *(const float4*)&A1t[c*68 + rt*4];
    const float4 w = *(const float4*)&W2[c*64 + ct*4];
    const float av[4]={a.x,a.y,a.z,a.w}, wv[4]={w.x,w.y,w.z,w.w};
#pragma unroll
    for(int i=0;i<4;i++)
#pragma unroll
      for(int j=0;j<4;j++) acc2[i][j] += av[i]*wv[j];
  }
  float a2v[4][4];
#pragma unroll
  for(int j=0;j<4;j++){
    const int o=ct*4+j; const float A=af2A[o], Bc=af2B[o];
#pragma unroll
    for(int i=0;i<4;i++) a2v[i][j]=fmaxf(acc2[i][j]*A+Bc, 0.f);
  }
  __syncthreads();
#pragma unroll
  for(int j=0;j<4;j++)
#pragma unroll
    for(int i=0;i<4;i++) A1t[(ct*4+j)*68 + rt*4+i] = a2v[i][j];
  __syncthreads();
  float acc3[4][8];
#pragma unroll
  for(int i=0;i<4;i++)
#pragma unroll
    for(int j=0;j<8;j++) acc3[i][j]=0.f;
#pragma unroll
  for(int c=0;c<64;c++){
    const float4 a  = *(const float4*)&A1t[c*68 + rt*4];
    const float4 w0 = *(const float4*)&W3[c*128 + ct*8];
    const float4 w1 = *(const float4*)&W3[c*128 + ct*8 + 4];
    const float av[4]={a.x,a.y,a.z,a.w};
    const float wv[8]={w0.x,w0.y,w0.z,w0.w,w1.x,w1.y,w1.z,w1.w};
#pragma unroll
    for(int i=0;i<4;i++)
#pragma unroll
      for(int j=0;j<8;j++) acc3[i][j] += av[i]*wv[j];
  }
  const int g = rt>>3;
#pragma unroll
  for(int j=0;j<8;j++){
    const int o=ct*8+j;
    float lm=acc3[0][j], s=0.f, q=0.f;
#pragma unroll
    for(int i=0;i<4;i++){ float v=acc3[i][j]; lm=fmaxf(lm,v); s+=v; q+=v*v; }
    atomicMax(&mx[g*128+o], fkey(lm));
    atomicAdd(&s3b[g*128+o], s);
    atomicAdd(&q3b[g*128+o], q);
  }
  __syncthreads();
  {
    const int gg=tid>>7, o=tid&127;
    const int cid = blockIdx.x*2+gg;
    premax[(size_t)cid*128+o] = funkey(mx[tid]);
  }
  if(tid<128){
    float* ps = pstats + (size_t)(blockIdx.x & (NREP-1))*512;
    atomicAdd(&ps[256+tid], s3b[tid]+s3b[128+tid]);
    atomicAdd(&ps[384+tid], q3b[tid]+q3b[128+tid]);
  }
}

// ------------------------------------------- layer-3 LEAN: reads materialized Z2
__global__ __launch_bounds__(256) void k_layer3z(const float* __restrict__ Z2,
                                                 const float* __restrict__ g2,
                                                 const float* __restrict__ b2,
                                                 const float* __restrict__ W3,
                                                 float* __restrict__ pstats,
                                                 float* __restrict__ premax){
  __shared__ __align__(16) float A2t[64*68];
  __shared__ float af2A[64], af2B[64];
  __shared__ unsigned mx[256];
  __shared__ float s3b[256], q3b[256];
  const int tid=threadIdx.x;
  if(tid<64){
    float sm2 = fold_rep(pstats, 128+tid);
    float sq2 = fold_rep(pstats, 192+tid);
    float m2 = sm2/RNF;
    float v2 = sq2/RNF - m2*m2;
    float A2 = rsqrtf(v2+EPSV)*g2[tid];
    af2A[tid]=A2; af2B[tid]=b2[tid]-m2*A2;
  }
  mx[tid]=0u; s3b[tid]=0.f; q3b[tid]=0.f;
  __syncthreads();
  {
    const int row = tid>>2, cq = (tid&3)*16;
    const float* zr = Z2 + ((size_t)blockIdx.x*64 + row)*64 + cq;
    const float4 z0 = *(const float4*)(zr);
    const float4 z1 = *(const float4*)(zr+4);
    const float4 z2 = *(const float4*)(zr+8);
    const float4 z3 = *(const float4*)(zr+12);
    const float zz[16]={z0.x,z0.y,z0.z,z0.w, z1.x,z1.y,z1.z,z1.w,
                        z2.x,z2.y,z2.z,z2.w, z3.x,z3.y,z3.z,z3.w};
#pragma unroll
    for(int u=0;u<16;u++){
      const int c = cq+u;
      A2t[c*68+row] = fmaxf(zz[u]*af2A[c]+af2B[c], 0.f);
    }
  }
  __syncthreads();
  const int rt=tid&15, ct=tid>>4;
  float acc3[4][8];
#pragma unroll
  for(int i=0;i<4;i++)
#pragma unroll
    for(int j=0;j<8;j++) acc3[i][j]=0.f;
#pragma unroll
  for(int c=0;c<64;c++){
    const float4 a  = *(const float4*)&A2t[c*68 + rt*4];
    const float4 w0 = *(const float4*)&W3[c*128 + ct*8];
    const float4 w1 = *(const float4*)&W3[c*128 + ct*8 + 4];
    const float av[4]={a.x,a.y,a.z,a.w};
    const float wv[8]={w0.x,w0.y,w0.z,w0.w,w1.x,w1.y,w1.z,w1.w};
#pragma unroll
    for(int i=0;i<4;i++)
#pragma unroll
      for(int j=0;j<8;j++) acc3[i][j] += av[i]*wv[j];
  }
  const int g = rt>>3;
#pragma unroll
  for(int j=0;j<8;j++){
    const int o=ct*8+j;
    float lm=acc3[0][j], s=0.f, q=0.f;
#pragma unroll
    for(int i=0;i<4;i++){ float v=acc3[i][j]; lm=fmaxf(lm,v); s+=v; q+=v*v; }
    atomicMax(&mx[g*128+o], fkey(lm));
    atomicAdd(&s3b[g*128+o], s);
    atomicAdd(&q3b[g*128+o], q);
  }
  __syncthreads();
  {
    const int gg=tid>>7, o=tid&127;
    const int cid = blockIdx.x*2+gg;
    premax[(size_t)cid*128+o] = funkey(mx[tid]);
  }
  if(tid<128){
    float* ps = pstats + (size_t)(blockIdx.x & (NREP-1))*512;
    atomicAdd(&ps[256+tid], s3b[tid]+s3b[128+tid]);
    atomicAdd(&ps[384+tid], q3b[tid]+q3b[128+tid]);
  }
}

// ------------------------------------------- fold layer-3 partials -> cstats
__global__ __launch_bounds__(256) void k_red3(const float* __restrict__ pstats,
                                              float* __restrict__ cstats){
  const int t = threadIdx.x;   // 256: [0..127]=sums, [128..255]=sumsq
  cstats[t] = fold_rep(pstats, 256+t);
}

// ------------------------------------------- final BN+relu (in place on outf)
__global__ __launch_bounds__(256) void k_final(const float* __restrict__ cstats,
                                               const float* __restrict__ g3,
                                               const float* __restrict__ b3,
                                               float* __restrict__ outf){
  const int i = blockIdx.x*256 + threadIdx.x;
  const int o = i & 127;
  float m  = cstats[o]/RNF;
  float vv = cstats[128+o]/RNF - m*m;
  float A  = rsqrtf(vv+EPSV)*g3[o];
  float Bc = b3[o]-m*A;
  float v  = outf[i];
  outf[i] = fmaxf(v*A+Bc, 0.f);
}

extern "C" void kernel_launch(void* const* d_in, const int* in_sizes, int n_in,
                              void* d_out, int out_size, void* d_ws, size_t ws_size,
                              hipStream_t stream){
  const float* xyz  = (const float*)d_in[0];
  const float* feat = (const float*)d_in[1];
  const float* W1   = (const float*)d_in[2];
  const float* g1   = (const float*)d_in[3];
  const float* b1   = (const float*)d_in[4];
  const float* W2   = (const float*)d_in[5];
  const float* g2   = (const float*)d_in[6];
  const float* b2   = (const float*)d_in[7];
  const float* W3   = (const float*)d_in[8];
  const float* g3   = (const float*)d_in[9];
  const float* b3   = (const float*)d_in[10];
  float* out  = (float*)d_out;
  float* cxyz = out;                     // (16,1024,3)
  float* outf = out + 16*1024*3;         // (16,1024,128) — premax staging then final
  // ws layout: [pstats 64x512 f32 @0 (128KB)][cstats 256 f32 @131072]
  //            [gidx 2MB @133120][Z2 134MB @2230272 (fast path)]
  float* pstats = (float*)d_ws;
  float* cstats = (float*)((char*)d_ws + 131072);
  int*   gidx   = (int*)((char*)d_ws + 133120);
  float* Z2     = (float*)((char*)d_ws + 133120 + (size_t)RTOT*4);
  const size_t need = 133120 + (size_t)RTOT*4 + (size_t)RTOT*64*4;  // ≈136.4 MB
  const bool fast = (ws_size >= need);   // ws_size constant per harness → same path every call

  hipMemsetAsync(pstats, 0, (size_t)NREP*512*sizeof(float), stream);
  k_fps   <<<16,   256,  0, stream>>>(xyz, cxyz);
  k_select<<<4096, 256,  0, stream>>>(xyz, cxyz, gidx);
  k_stats1<<<8192, 256,  0, stream>>>(xyz, feat, cxyz, gidx, W1, pstats);
  if(fast){
    k_stats2m<<<8192, 256, 0, stream>>>(xyz, feat, cxyz, gidx, W1, g1, b1, W2, pstats, Z2);
    k_layer3z<<<8192, 256, 0, stream>>>(Z2, g2, b2, W3, pstats, outf);
  }else{
    k_stats2 <<<8192, 256, 0, stream>>>(xyz, feat, cxyz, gidx, W1, g1, b1, W2, pstats);
    k_layer3 <<<8192, 256, 0, stream>>>(xyz, feat, cxyz, gidx, W1, g1, b1, W2, g2, b2, W3, pstats, outf);
  }
  k_red3  <<<1,    256,  0, stream>>>(pstats, cstats);
  k_final <<<8192, 256,  0, stream>>>(cstats, g3, b3, outf);
}

// Round 16
// 1666.709 us; speedup vs baseline: 1.0942x; 1.0942x over previous
//
#include <hip/hip_runtime.h>

#define BN_   16
#define NPTS  4096
#define DFEAT 6
#define SCTR  1024
#define KNN   32
#define RTOT  (BN_*SCTR*KNN)   /* 524288 rows */
#define EPSV  1e-5f
#define RNF   524288.0f
#define NREP  64               /* replicated stats copies */

__device__ __forceinline__ float fmulx(float a, float b){ return __fmul_rn(a,b); }
__device__ __forceinline__ float faddx(float a, float b){ return __fadd_rn(a,b); }
__device__ __forceinline__ float fsubx(float a, float b){ return __fsub_rn(a,b); }
// naive (non-FMA) sum of squares — LOCKED by R5/R6 pass.
__device__ __forceinline__ float sq3x(float x, float y, float z){
  return faddx(faddx(fmulx(x,x), fmulx(y,y)), fmulx(z,z));
}
// FMA-contracted inner product (matches np einsum) — LOCKED by R5 pass.
__device__ __forceinline__ float dot3fma(float ax, float ay, float az,
                                         float bx, float by, float bz){
  return __fmaf_rn(az, bz, __fmaf_rn(ay, by, __fmul_rn(ax, bx)));
}

__device__ __forceinline__ unsigned fkey(float f){
  unsigned u = __float_as_uint(f);
  return (u & 0x80000000u) ? ~u : (u | 0x80000000u);
}
__device__ __forceinline__ float funkey(unsigned k){
  return (k & 0x80000000u) ? __uint_as_float(k & 0x7fffffffu) : __uint_as_float(~k);
}

// ---------------- DPP wave64 reductions (VALU-only; proven on HW in R12).
template<int CTRL>
__device__ __forceinline__ unsigned dpp_mv(unsigned v){
  return (unsigned)__builtin_amdgcn_update_dpp((int)v, (int)v, CTRL, 0xf, 0xf, false);
}
__device__ __forceinline__ unsigned wave_umax_b(unsigned v){
  unsigned o;
  o=dpp_mv<0x111>(v); v=v>o?v:o;   // row_shr:1
  o=dpp_mv<0x112>(v); v=v>o?v:o;   // row_shr:2
  o=dpp_mv<0x114>(v); v=v>o?v:o;   // row_shr:4
  o=dpp_mv<0x118>(v); v=v>o?v:o;   // row_shr:8
  o=dpp_mv<0x142>(v); v=v>o?v:o;   // row_bcast:15
  o=dpp_mv<0x143>(v); v=v>o?v:o;   // row_bcast:31
  return (unsigned)__builtin_amdgcn_readlane((int)v, 63);
}
__device__ __forceinline__ unsigned wave_umin_b(unsigned v){
  unsigned o;
  o=dpp_mv<0x111>(v); v=v<o?v:o;
  o=dpp_mv<0x112>(v); v=v<o?v:o;
  o=dpp_mv<0x114>(v); v=v<o?v:o;
  o=dpp_mv<0x118>(v); v=v<o?v:o;
  o=dpp_mv<0x142>(v); v=v<o?v:o;
  o=dpp_mv<0x143>(v); v=v<o?v:o;
  return (unsigned)__builtin_amdgcn_readlane((int)v, 63);
}

// ---------------------------------------------------------------- FPS
// R12/R14 proven version (623 µs): s_barrier per iter, DPP two-phase argmax,
// winner coords from LDS. R15's LDS spin-poll regressed (782 µs) — barrier
// at 4 waves/block beats software polling. Do not reintroduce.
__global__ __launch_bounds__(256) void k_fps(const float* __restrict__ xyz,
                                             float* __restrict__ cxyz){
  const int b = blockIdx.x, tid = threadIdx.x;
  const int wave = tid>>6, lane = tid&63;
  const float* X = xyz + (size_t)b*NPTS*3;
  __shared__ float Xl[NPTS*3];
  __shared__ float Cl[SCTR*3];
  __shared__ unsigned long long slot[2][4];
  for(int i=tid;i<NPTS*3;i+=256) Xl[i]=X[i];
  __syncthreads();
  float px[16],py[16],pz[16],mind[16];
  const float c0x=Xl[0], c0y=Xl[1], c0z=Xl[2];
#pragma unroll
  for(int t=0;t<16;t++){
    const int j = lane + 64*(wave*16+t);
    px[t]=Xl[j*3]; py[t]=Xl[j*3+1]; pz[t]=Xl[j*3+2];
    mind[t]=sq3x(fsubx(px[t],c0x), fsubx(py[t],c0y), fsubx(pz[t],c0z));
  }
  if(tid==0){ Cl[0]=c0x; Cl[1]=c0y; Cl[2]=c0z; }
  float bv=-1.0f; int bj=0x7fffffff;
#pragma unroll
  for(int t=0;t<16;t++){
    const int j = lane + 64*(wave*16+t);
    if(mind[t]>bv){ bv=mind[t]; bj=j; }
  }
  for(int it=1; it<SCTR; ++it){
    const unsigned uv = __float_as_uint(bv);
    const unsigned M  = wave_umax_b(uv);
    const unsigned nj = (uv == M) ? ~(unsigned)bj : 0u;
    const unsigned NJ = wave_umax_b(nj);
    if(lane==0) slot[it&1][wave] = ((unsigned long long)M<<32) | NJ;
    __syncthreads();          // parity double-buffer prevents WAR
    unsigned long long k0=slot[it&1][0], k1=slot[it&1][1],
                       k2=slot[it&1][2], k3=slot[it&1][3];
    unsigned long long ka = k0>k1?k0:k1;
    unsigned long long kb = k2>k3?k2:k3;
    unsigned long long kw = ka>kb?ka:kb;
    const int w = (int)(~(unsigned)kw);          // j < 4096
    const float cx=Xl[w*3], cy=Xl[w*3+1], cz=Xl[w*3+2];
    if(tid==0){ Cl[it*3]=cx; Cl[it*3+1]=cy; Cl[it*3+2]=cz; }
    bv=-1.0f; bj=0x7fffffff;
#pragma unroll
    for(int t=0;t<16;t++){
      float d = sq3x(fsubx(px[t],cx), fsubx(py[t],cy), fsubx(pz[t],cz));
      float nm = fminf(mind[t], d);
      mind[t]=nm;
      const int j = lane + 64*(wave*16+t);
      if(nm>bv){ bv=nm; bj=j; }
    }
  }
  __syncthreads();
  float* O = cxyz + (size_t)b*SCTR*3;
  for(int i=tid;i<SCTR*3;i+=256) O[i]=Cl[i];
}

// ------------------------------------------- 32-NN select (R12 version, proven)
__global__ __launch_bounds__(256) void k_select(const float* __restrict__ xyz,
                                                const float* __restrict__ cxyz,
                                                int* __restrict__ gidx){
  const int lane = threadIdx.x & 63;
  const int cid  = blockIdx.x*4 + (threadIdx.x>>6);
  const int b = cid>>10;
  const float* X = xyz + (size_t)b*NPTS*3;
  const float* C = cxyz + (size_t)cid*3;
  const float cx=C[0], cy=C[1], cz=C[2];
  const float a2 = sq3x(cx,cy,cz);
  float d[64];
#pragma unroll
  for(int t=0;t<64;t++){
    int j = lane + (t<<6);
    float x=X[j*3], y=X[j*3+1], z=X[j*3+2];
    float b2 = sq3x(x,y,z);
    float dt = dot3fma(cx,cy,cz, x,y,z);
    float dd = fsubx(faddx(a2,b2), fmulx(2.0f,dt));
    d[t] = fmaxf(dd, 0.0f);
  }
  unsigned long long taken = 0ull;
  int* out = gidx + (size_t)cid*KNN;
#pragma unroll 1
  for(int r=0;r<KNN;r++){
    float mv = 3.0e38f; int mt = 63;
#pragma unroll
    for(int t=0;t<64;t++){
      if(!(taken & (1ull<<t)) && d[t] < mv){ mv = d[t]; mt = t; }
    }
    const unsigned um = __float_as_uint(mv);
    const unsigned Mw = wave_umin_b(um);
    const unsigned jc = (um == Mw) ? (unsigned)(lane + (mt<<6)) : 0xffffffffu;
    const unsigned WJ = wave_umin_b(jc);
    if(lane == (int)(WJ & 63u)){
      out[r] = (int)WJ;
      taken |= (1ull << (WJ >> 6));
    }
  }
}

// ------------------------------------------------- shared tile helpers
__device__ __forceinline__ void stage_in(float* INt, int rbase,
                                         const float* __restrict__ xyz,
                                         const float* __restrict__ feat,
                                         const float* __restrict__ cxyz,
                                         const int* __restrict__ gidx){
  const int tid = threadIdx.x;
  const int row = tid>>2, sub = tid&3;
  const int r  = rbase + row;
  const int bb = r>>15, ss=(r>>5)&1023;
  const int idx = gidx[r];
  if(sub==0){
    const float* P = xyz  + ((size_t)bb*NPTS + idx)*3;
    const float* C = cxyz + ((size_t)(bb*SCTR)+ss)*3;
    INt[0*68+row] = P[0]-C[0];
    INt[1*68+row] = P[1]-C[1];
    INt[2*68+row] = P[2]-C[2];
  }else{
    const float* F = feat + ((size_t)bb*NPTS + idx)*6;
    const int c = (sub-1)*2;
    INt[(3+c)*68+row] = F[c];
    INt[(4+c)*68+row] = F[c+1];
  }
}

__device__ __forceinline__ void gemm1(const float* INt, const float* __restrict__ W1,
                                      int rt, int ct, float acc[4][4]){
#pragma unroll
  for(int i=0;i<4;i++)
#pragma unroll
    for(int j=0;j<4;j++) acc[i][j]=0.f;
#pragma unroll
  for(int c=0;c<9;c++){
    const float4 a = *(const float4*)&INt[c*68 + rt*4];
    const float4 w = *(const float4*)&W1[c*64 + ct*4];
    const float av[4]={a.x,a.y,a.z,a.w}, wv[4]={w.x,w.y,w.z,w.w};
#pragma unroll
    for(int i=0;i<4;i++)
#pragma unroll
      for(int j=0;j<4;j++) acc[i][j] += av[i]*wv[j];
  }
}

// fold one channel across the NREP replicated copies
__device__ __forceinline__ float fold_rep(const float* __restrict__ pstats, int off){
  float s=0.f;
#pragma unroll 8
  for(int c=0;c<NREP;c++) s += pstats[c*512 + off];
  return s;
}

// ---------------------------------------------------------------- layer-1 stats
__global__ __launch_bounds__(256) void k_stats1(const float* __restrict__ xyz,
                                                const float* __restrict__ feat,
                                                const float* __restrict__ cxyz,
                                                const int* __restrict__ gidx,
                                                const float* __restrict__ W1,
                                                float* __restrict__ pstats){
  __shared__ __align__(16) float INt[9*68];
  __shared__ float sb[64], qb[64];
  const int tid=threadIdx.x;
  if(tid<64){ sb[tid]=0.f; qb[tid]=0.f; }
  stage_in(INt, blockIdx.x*64, xyz, feat, cxyz, gidx);
  __syncthreads();
  const int rt=tid&15, ct=tid>>4;
  float acc[4][4];
  gemm1(INt, W1, rt, ct, acc);
#pragma unroll
  for(int j=0;j<4;j++){
    float s=0.f, q=0.f;
#pragma unroll
    for(int i=0;i<4;i++){ float v=acc[i][j]; s+=v; q+=v*v; }
    atomicAdd(&sb[ct*4+j], s); atomicAdd(&qb[ct*4+j], q);
  }
  __syncthreads();
  if(tid<64){
    float* ps = pstats + (size_t)(blockIdx.x & (NREP-1))*512;
    atomicAdd(&ps[tid], sb[tid]); atomicAdd(&ps[64+tid], qb[tid]);
  }
}

// -------------------------------------- layer-2 stats core (optionally writes Z2)
template<bool WRITEZ>
__device__ __forceinline__ void stats2_body(const float* xyz, const float* feat,
                                            const float* cxyz, const int* gidx,
                                            const float* W1, const float* g1,
                                            const float* b1, const float* __restrict__ W2,
                                            float* pstats, float* Z2){
  __shared__ __align__(16) float INt[9*68];
  __shared__ __align__(16) float A1t[64*68];
  __shared__ float af1A[64], af1B[64];
  __shared__ float sb[64], qb[64];
  const int tid=threadIdx.x;
  if(tid<64){
    float sm = fold_rep(pstats, tid);
    float sq = fold_rep(pstats, 64+tid);
    float m  = sm/RNF;
    float vv = sq/RNF - m*m;
    float A  = rsqrtf(vv+EPSV)*g1[tid];
    af1A[tid]=A; af1B[tid]=b1[tid]-m*A;
    sb[tid]=0.f; qb[tid]=0.f;
  }
  stage_in(INt, blockIdx.x*64, xyz, feat, cxyz, gidx);
  __syncthreads();
  const int rt=tid&15, ct=tid>>4;
  float acc1[4][4];
  gemm1(INt, W1, rt, ct, acc1);
#pragma unroll
  for(int j=0;j<4;j++){
    const int o=ct*4+j; const float A=af1A[o], Bc=af1B[o];
#pragma unroll
    for(int i=0;i<4;i++) A1t[o*68 + rt*4+i] = fmaxf(acc1[i][j]*A+Bc, 0.f);
  }
  __syncthreads();
  float acc2[4][4];
#pragma unroll
  for(int i=0;i<4;i++)
#pragma unroll
    for(int j=0;j<4;j++) acc2[i][j]=0.f;
#pragma unroll
  for(int c=0;c<64;c++){
    const float4 a = *(const float4*)&A1t[c*68 + rt*4];
    const float4 w = *(const float4*)&W2[c*64 + ct*4];
    const float av[4]={a.x,a.y,a.z,a.w}, wv[4]={w.x,w.y,w.z,w.w};
#pragma unroll
    for(int i=0;i<4;i++)
#pragma unroll
      for(int j=0;j<4;j++) acc2[i][j] += av[i]*wv[j];
  }
  if(WRITEZ){
#pragma unroll
    for(int i=0;i<4;i++){
      float4 v = make_float4(acc2[i][0],acc2[i][1],acc2[i][2],acc2[i][3]);
      *(float4*)&Z2[((size_t)blockIdx.x*64 + rt*4+i)*64 + ct*4] = v;
    }
  }
#pragma unroll
  for(int j=0;j<4;j++){
    float s=0.f, q=0.f;
#pragma unroll
    for(int i=0;i<4;i++){ float v=acc2[i][j]; s+=v; q+=v*v; }
    atomicAdd(&sb[ct*4+j], s); atomicAdd(&qb[ct*4+j], q);
  }
  __syncthreads();
  if(tid<64){
    float* ps = pstats + (size_t)(blockIdx.x & (NREP-1))*512;
    atomicAdd(&ps[128+tid], sb[tid]); atomicAdd(&ps[192+tid], qb[tid]);
  }
}

__global__ __launch_bounds__(256) void k_stats2(const float* __restrict__ xyz,
                                                const float* __restrict__ feat,
                                                const float* __restrict__ cxyz,
                                                const int* __restrict__ gidx,
                                                const float* __restrict__ W1,
                                                const float* __restrict__ g1,
                                                const float* __restrict__ b1,
                                                const float* __restrict__ W2,
                                                float* __restrict__ pstats){
  stats2_body<false>(xyz,feat,cxyz,gidx,W1,g1,b1,W2,pstats,nullptr);
}
__global__ __launch_bounds__(256) void k_stats2m(const float* __restrict__ xyz,
                                                 const float* __restrict__ feat,
                                                 const float* __restrict__ cxyz,
                                                 const int* __restrict__ gidx,
                                                 const float* __restrict__ W1,
                                                 const float* __restrict__ g1,
                                                 const float* __restrict__ b1,
                                                 const float* __restrict__ W2,
                                                 float* __restrict__ pstats,
                                                 float* __restrict__ Z2){
  stats2_body<true>(xyz,feat,cxyz,gidx,W1,g1,b1,W2,pstats,Z2);
}

// ------------------------------------------- layer-3 (fallback: full recompute)
__global__ __launch_bounds__(256) void k_layer3(const float* __restrict__ xyz,
                                                const float* __restrict__ feat,
                                                const float* __restrict__ cxyz,
                                                const int* __restrict__ gidx,
                                                const float* __restrict__ W1,
                                                const float* __restrict__ g1,
                                                const float* __restrict__ b1,
                                                const float* __restrict__ W2,
                                                const float* __restrict__ g2,
                                                const float* __restrict__ b2,
                                                const float* __restrict__ W3,
                                                float* __restrict__ pstats,
                                                float* __restrict__ premax){
  __shared__ __align__(16) float INt[9*68];
  __shared__ __align__(16) float A1t[64*68];
  __shared__ float af1A[64], af1B[64], af2A[64], af2B[64];
  __shared__ unsigned mx[256];
  __shared__ float s3b[256], q3b[256];
  const int tid=threadIdx.x;
  if(tid<64){
    float sm = fold_rep(pstats, tid);
    float sq = fold_rep(pstats, 64+tid);
    float m  = sm/RNF;
    float vv = sq/RNF - m*m;
    float A  = rsqrtf(vv+EPSV)*g1[tid];
    af1A[tid]=A; af1B[tid]=b1[tid]-m*A;
    float sm2 = fold_rep(pstats, 128+tid);
    float sq2 = fold_rep(pstats, 192+tid);
    float m2 = sm2/RNF;
    float v2 = sq2/RNF - m2*m2;
    float A2 = rsqrtf(v2+EPSV)*g2[tid];
    af2A[tid]=A2; af2B[tid]=b2[tid]-m2*A2;
  }
  mx[tid]=0u; s3b[tid]=0.f; q3b[tid]=0.f;
  stage_in(INt, blockIdx.x*64, xyz, feat, cxyz, gidx);
  __syncthreads();
  const int rt=tid&15, ct=tid>>4;
  float acc1[4][4];
  gemm1(INt, W1, rt, ct, acc1);
#pragma unroll
  for(int j=0;j<4;j++){
    const int o=ct*4+j; const float A=af1A[o], Bc=af1B[o];
#pragma unroll
    for(int i=0;i<4;i++) A1t[o*68 + rt*4+i] = fmaxf(acc1[i][j]*A+Bc, 0.f);
  }
  __syncthreads();
  float acc2[4][4];
#pragma unroll
  for(int i=0;i<4;i++)
#pragma unroll
    for(int j=0;j<4;j++) acc2[i][j]=0.f;
#pragma unroll
  for(int c=0;c<64;c++){
    const float4 a = *(const float4*)&A1t[c*68 + rt*4];
    const float4 w = *(const float4*)&W2[c*64 + ct*4];
    const float av[4]={a.x,a.y,a.z,a.w}, wv[4]={w.x,w.y,w.z,w.w};
#pragma unroll
    for(int i=0;i<4;i++)
#pragma unroll
      for(int j=0;j<4;j++) acc2[i][j] += av[i]*wv[j];
  }
  float a2v[4][4];
#pragma unroll
  for(int j=0;j<4;j++){
    const int o=ct*4+j; const float A=af2A[o], Bc=af2B[o];
#pragma unroll
    for(int i=0;i<4;i++) a2v[i][j]=fmaxf(acc2[i][j]*A+Bc, 0.f);
  }
  __syncthreads();
#pragma unroll
  for(int j=0;j<4;j++)
#pragma unroll
    for(int i=0;i<4;i++) A1t[(ct*4+j)*68 + rt*4+i] = a2v[i][j];
  __syncthreads();
  float acc3[4][8];
#pragma unroll
  for(int i=0;i<4;i++)
#pragma unroll
    for(int j=0;j<8;j++) acc3[i][j]=0.f;
#pragma unroll
  for(int c=0;c<64;c++){
    const float4 a  = *(const float4*)&A1t[c*68 + rt*4];
    const float4 w0 = *(const float4*)&W3[c*128 + ct*8];
    const float4 w1 = *(const float4*)&W3[c*128 + ct*8 + 4];
    const float av[4]={a.x,a.y,a.z,a.w};
    const float wv[8]={w0.x,w0.y,w0.z,w0.w,w1.x,w1.y,w1.z,w1.w};
#pragma unroll
    for(int i=0;i<4;i++)
#pragma unroll
      for(int j=0;j<8;j++) acc3[i][j] += av[i]*wv[j];
  }
  const int g = rt>>3;
#pragma unroll
  for(int j=0;j<8;j++){
    const int o=ct*8+j;
    float lm=acc3[0][j], s=0.f, q=0.f;
#pragma unroll
    for(int i=0;i<4;i++){ float v=acc3[i][j]; lm=fmaxf(lm,v); s+=v; q+=v*v; }
    atomicMax(&mx[g*128+o], fkey(lm));
    atomicAdd(&s3b[g*128+o], s);
    atomicAdd(&q3b[g*128+o], q);
  }
  __syncthreads();
  {
    const int gg=tid>>7, o=tid&127;
    const int cid = blockIdx.x*2+gg;
    premax[(size_t)cid*128+o] = funkey(mx[tid]);
  }
  if(tid<128){
    float* ps = pstats + (size_t)(blockIdx.x & (NREP-1))*512;
    atomicAdd(&ps[256+tid], s3b[tid]+s3b[128+tid]);
    atomicAdd(&ps[384+tid], q3b[tid]+q3b[128+tid]);
  }
}

// ------------------------------------------- layer-3 LEAN: reads materialized Z2
__global__ __launch_bounds__(256) void k_layer3z(const float* __restrict__ Z2,
                                                 const float* __restrict__ g2,
                                                 const float* __restrict__ b2,
                                                 const float* __restrict__ W3,
                                                 float* __restrict__ pstats,
                                                 float* __restrict__ premax){
  __shared__ __align__(16) float A2t[64*68];
  __shared__ float af2A[64], af2B[64];
  __shared__ unsigned mx[256];
  __shared__ float s3b[256], q3b[256];
  const int tid=threadIdx.x;
  if(tid<64){
    float sm2 = fold_rep(pstats, 128+tid);
    float sq2 = fold_rep(pstats, 192+tid);
    float m2 = sm2/RNF;
    float v2 = sq2/RNF - m2*m2;
    float A2 = rsqrtf(v2+EPSV)*g2[tid];
    af2A[tid]=A2; af2B[tid]=b2[tid]-m2*A2;
  }
  mx[tid]=0u; s3b[tid]=0.f; q3b[tid]=0.f;
  __syncthreads();
  {
    const int row = tid>>2, cq = (tid&3)*16;
    const float* zr = Z2 + ((size_t)blockIdx.x*64 + row)*64 + cq;
    const float4 z0 = *(const float4*)(zr);
    const float4 z1 = *(const float4*)(zr+4);
    const float4 z2 = *(const float4*)(zr+8);
    const float4 z3 = *(const float4*)(zr+12);
    const float zz[16]={z0.x,z0.y,z0.z,z0.w, z1.x,z1.y,z1.z,z1.w,
                        z2.x,z2.y,z2.z,z2.w, z3.x,z3.y,z3.z,z3.w};
#pragma unroll
    for(int u=0;u<16;u++){
      const int c = cq+u;
      A2t[c*68+row] = fmaxf(zz[u]*af2A[c]+af2B[c], 0.f);
    }
  }
  __syncthreads();
  const int rt=tid&15, ct=tid>>4;
  float acc3[4][8];
#pragma unroll
  for(int i=0;i<4;i++)
#pragma unroll
    for(int j=0;j<8;j++) acc3[i][j]=0.f;
#pragma unroll
  for(int c=0;c<64;c++){
    const float4 a  = *(const float4*)&A2t[c*68 + rt*4];
    const float4 w0 = *(const float4*)&W3[c*128 + ct*8];
    const float4 w1 = *(const float4*)&W3[c*128 + ct*8 + 4];
    const float av[4]={a.x,a.y,a.z,a.w};
    const float wv[8]={w0.x,w0.y,w0.z,w0.w,w1.x,w1.y,w1.z,w1.w};
#pragma unroll
    for(int i=0;i<4;i++)
#pragma unroll
      for(int j=0;j<8;j++) acc3[i][j] += av[i]*wv[j];
  }
  const int g = rt>>3;
#pragma unroll
  for(int j=0;j<8;j++){
    const int o=ct*8+j;
    float lm=acc3[0][j], s=0.f, q=0.f;
#pragma unroll
    for(int i=0;i<4;i++){ float v=acc3[i][j]; lm=fmaxf(lm,v); s+=v; q+=v*v; }
    atomicMax(&mx[g*128+o], fkey(lm));
    atomicAdd(&s3b[g*128+o], s);
    atomicAdd(&q3b[g*128+o], q);
  }
  __syncthreads();
  {
    const int gg=tid>>7, o=tid&127;
    const int cid = blockIdx.x*2+gg;
    premax[(size_t)cid*128+o] = funkey(mx[tid]);
  }
  if(tid<128){
    float* ps = pstats + (size_t)(blockIdx.x & (NREP-1))*512;
    atomicAdd(&ps[256+tid], s3b[tid]+s3b[128+tid]);
    atomicAdd(&ps[384+tid], q3b[tid]+q3b[128+tid]);
  }
}

// ------------------------------------------- fold layer-3 partials -> cstats
__global__ __launch_bounds__(256) void k_red3(const float* __restrict__ pstats,
                                              float* __restrict__ cstats){
  const int t = threadIdx.x;   // 256: [0..127]=sums, [128..255]=sumsq
  cstats[t] = fold_rep(pstats, 256+t);
}

// ------------------------------------------- final BN+relu (in place on outf)
__global__ __launch_bounds__(256) void k_final(const float* __restrict__ cstats,
                                               const float* __restrict__ g3,
                                               const float* __restrict__ b3,
                                               float* __restrict__ outf){
  const int i = blockIdx.x*256 + threadIdx.x;
  const int o = i & 127;
  float m  = cstats[o]/RNF;
  float vv = cstats[128+o]/RNF - m*m;
  float A  = rsqrtf(vv+EPSV)*g3[o];
  float Bc = b3[o]-m*A;
  float v  = outf[i];
  outf[i] = fmaxf(v*A+Bc, 0.f);
}

extern "C" void kernel_launch(void* const* d_in, const int* in_sizes, int n_in,
                              void* d_out, int out_size, void* d_ws, size_t ws_size,
                              hipStream_t stream){
  const float* xyz  = (const float*)d_in[0];
  const float* feat = (const float*)d_in[1];
  const float* W1   = (const float*)d_in[2];
  const float* g1   = (const float*)d_in[3];
  const float* b1   = (const float*)d_in[4];
  const float* W2   = (const float*)d_in[5];
  const float* g2   = (const float*)d_in[6];
  const float* b2   = (const float*)d_in[7];
  const float* W3   = (const float*)d_in[8];
  const float* g3   = (const float*)d_in[9];
  const float* b3   = (const float*)d_in[10];
  float* out  = (float*)d_out;
  float* cxyz = out;                     // (16,1024,3)
  float* outf = out + 16*1024*3;         // (16,1024,128) — premax staging then final
  // ws layout: [pstats 64x512 f32 @0 (128KB)][cstats 256 f32 @131072]
  //            [gidx 2MB @133120][Z2 134MB @2230272 (fast path)]
  float* pstats = (float*)d_ws;
  float* cstats = (float*)((char*)d_ws + 131072);
  int*   gidx   = (int*)((char*)d_ws + 133120);
  float* Z2     = (float*)((char*)d_ws + 133120 + (size_t)RTOT*4);
  const size_t need = 133120 + (size_t)RTOT*4 + (size_t)RTOT*64*4;  // ≈136.4 MB
  const bool fast = (ws_size >= need);   // ws_size constant per harness → same path every call

  hipMemsetAsync(pstats, 0, (size_t)NREP*512*sizeof(float), stream);
  k_fps   <<<16,   256,  0, stream>>>(xyz, cxyz);
  k_select<<<4096, 256,  0, stream>>>(xyz, cxyz, gidx);
  k_stats1<<<8192, 256,  0, stream>>>(xyz, feat, cxyz, gidx, W1, pstats);
  if(fast){
    k_stats2m<<<8192, 256, 0, stream>>>(xyz, feat, cxyz, gidx, W1, g1, b1, W2, pstats, Z2);
    k_layer3z<<<8192, 256, 0, stream>>>(Z2, g2, b2, W3, pstats, outf);
  }else{
    k_stats2 <<<8192, 256, 0, stream>>>(xyz, feat, cxyz, gidx, W1, g1, b1, W2, pstats);
    k_layer3 <<<8192, 256, 0, stream>>>(xyz, feat, cxyz, gidx, W1, g1, b1, W2, g2, b2, W3, pstats, outf);
  }
  k_red3  <<<1,    256,  0, stream>>>(pstats, cstats);
  k_final <<<8192, 256,  0, stream>>>(cstats, g3, b3, outf);
}